// Round 1
// baseline (571.659 us; speedup 1.0000x reference)
//
#include <hip/hip_runtime.h>
#include <hip/hip_bf16.h>

// B=4, S=2048, D=1024, E=HEAD*DIM=1024, DIM=64 -> scale = 0.125
// softmax quirk: normalized over the QUERY axis (columns of scores^T view):
//   attn[b,q,k] = exp(s[b,q,k] - m[b,k]) / sum_q' exp(s[b,q',k] - m[b,k])
//
// All GEMMs done with split-bf16 (hi+lo) MFMA => ~fp32 accuracy.
// Workspace layout (floats), total ~185 MB (assumes ws_size >= ~190MB):
//   Wqt,Wkt,Wvt,Wot : 4 * 1024*1024
//   Qp   : 8192*1024
//   Kp   : 8192*1024
//   Vt   : 4 * 1024*2048   (per-batch transposed V projection [e][s])
//   S    : 4 * 2048*2048   (scores, normalized in place to attn)
//   pm,pl: 8*8192 each ; mf,lf: 8192 each
//   head : reuses Qp (dead after scores GEMM)

typedef __bf16 bf16x8 __attribute__((ext_vector_type(8)));
typedef __bf16 bf16x4 __attribute__((ext_vector_type(4)));
typedef float f32x4 __attribute__((ext_vector_type(4)));

#define BM 128
#define BN 128
#define BK 32
#define LDST 40  // LDS row stride (elements) to break bank-conflict stride

// C[M,N] = scale * A[M,K] * B[N,K]^T   (NT form, A/B row-major fp32)
// TRANS: store C transposed (C[n*ldC + m]).
template <int SPLIT, int TRANS>
__global__ __launch_bounds__(256) void gemm_nt(
    const float* __restrict__ A, const float* __restrict__ B,
    float* __restrict__ C, int K, int ldA, int ldB, int ldC,
    long sA, long sB, long sC, float scale) {
  __shared__ __bf16 Ah[BM * LDST];
  __shared__ __bf16 Al[BM * LDST];
  __shared__ __bf16 Bh[BN * LDST];
  __shared__ __bf16 Bl[BN * LDST];

  const int tid = threadIdx.x;
  const long bz = blockIdx.z;
  A += bz * sA;
  B += bz * sB;
  C += bz * sC;
  const int tM = blockIdx.y * BM;
  const int tN = blockIdx.x * BN;

  const int lane = tid & 63;
  const int wave = tid >> 6;
  const int wr = (wave >> 1) * 64;
  const int wc = (wave & 1) * 64;
  const int r16 = lane & 15;
  const int q4 = lane >> 4;   // 0..3
  const int kof = q4 * 8;

  f32x4 acc[4][4];
#pragma unroll
  for (int m = 0; m < 4; ++m)
#pragma unroll
    for (int n = 0; n < 4; ++n) acc[m][n] = {0.f, 0.f, 0.f, 0.f};

  for (int kt = 0; kt < K; kt += BK) {
    // stage A and B tiles [128][32] fp32 -> hi/lo bf16 in LDS
#pragma unroll
    for (int it = 0; it < 4; ++it) {
      int flat = it * 1024 + tid * 4;
      int row = flat >> 5;
      int col = flat & 31;
      float4 av = *reinterpret_cast<const float4*>(&A[(long)(tM + row) * ldA + kt + col]);
      float4 bv = *reinterpret_cast<const float4*>(&B[(long)(tN + row) * ldB + kt + col]);
      bf16x4 ah = {(__bf16)av.x, (__bf16)av.y, (__bf16)av.z, (__bf16)av.w};
      bf16x4 bh = {(__bf16)bv.x, (__bf16)bv.y, (__bf16)bv.z, (__bf16)bv.w};
      *reinterpret_cast<bf16x4*>(&Ah[row * LDST + col]) = ah;
      *reinterpret_cast<bf16x4*>(&Bh[row * LDST + col]) = bh;
      if (SPLIT) {
        bf16x4 al = {(__bf16)(av.x - (float)ah[0]), (__bf16)(av.y - (float)ah[1]),
                     (__bf16)(av.z - (float)ah[2]), (__bf16)(av.w - (float)ah[3])};
        bf16x4 bl = {(__bf16)(bv.x - (float)bh[0]), (__bf16)(bv.y - (float)bh[1]),
                     (__bf16)(bv.z - (float)bh[2]), (__bf16)(bv.w - (float)bh[3])};
        *reinterpret_cast<bf16x4*>(&Al[row * LDST + col]) = al;
        *reinterpret_cast<bf16x4*>(&Bl[row * LDST + col]) = bl;
      }
    }
    __syncthreads();

    bf16x8 afh[4], afl[4], bfh[4], bfl[4];
#pragma unroll
    for (int m = 0; m < 4; ++m) {
      int ar = wr + m * 16 + r16;
      afh[m] = *reinterpret_cast<const bf16x8*>(&Ah[ar * LDST + kof]);
      if (SPLIT) afl[m] = *reinterpret_cast<const bf16x8*>(&Al[ar * LDST + kof]);
    }
#pragma unroll
    for (int n = 0; n < 4; ++n) {
      int br = wc + n * 16 + r16;
      bfh[n] = *reinterpret_cast<const bf16x8*>(&Bh[br * LDST + kof]);
      if (SPLIT) bfl[n] = *reinterpret_cast<const bf16x8*>(&Bl[br * LDST + kof]);
    }
#pragma unroll
    for (int m = 0; m < 4; ++m)
#pragma unroll
      for (int n = 0; n < 4; ++n) {
        acc[m][n] = __builtin_amdgcn_mfma_f32_16x16x32_bf16(afh[m], bfh[n], acc[m][n], 0, 0, 0);
        if (SPLIT) {
          acc[m][n] = __builtin_amdgcn_mfma_f32_16x16x32_bf16(afh[m], bfl[n], acc[m][n], 0, 0, 0);
          acc[m][n] = __builtin_amdgcn_mfma_f32_16x16x32_bf16(afl[m], bfh[n], acc[m][n], 0, 0, 0);
        }
      }
    __syncthreads();
  }

#pragma unroll
  for (int m = 0; m < 4; ++m)
#pragma unroll
    for (int n = 0; n < 4; ++n)
#pragma unroll
      for (int j = 0; j < 4; ++j) {
        int rr = tM + wr + m * 16 + q4 * 4 + j;
        int cc = tN + wc + n * 16 + r16;
        float v = acc[m][n][j] * scale;
        if (TRANS)
          C[(long)cc * ldC + rr] = v;
        else
          C[(long)rr * ldC + cc] = v;
      }
}

__global__ void transpose_k(const float* __restrict__ in, float* __restrict__ out, int n) {
  __shared__ float t[32][33];
  int bx = blockIdx.x * 32, by = blockIdx.y * 32;
  int tx = threadIdx.x, ty = threadIdx.y;  // 32 x 8
  for (int i = 0; i < 32; i += 8) t[ty + i][tx] = in[(long)(by + ty + i) * n + bx + tx];
  __syncthreads();
  for (int i = 0; i < 32; i += 8) out[(long)(bx + ty + i) * n + by + tx] = t[tx][ty + i];
}

// per-column (over q) online max/sum, partial over a 256-row chunk
__global__ __launch_bounds__(256) void stats1(const float* __restrict__ S,
                                              float* __restrict__ pm, float* __restrict__ pl) {
  int b = blockIdx.z;
  int col = blockIdx.x * 256 + threadIdx.x;
  int q0 = blockIdx.y * 256;
  const float* Sb = S + (long)b * 2048 * 2048;
  float m = -1e30f, l = 0.f;
  for (int i = 0; i < 256; ++i) {
    float s = Sb[(long)(q0 + i) * 2048 + col];
    float mn = fmaxf(m, s);
    l = l * __expf(m - mn) + __expf(s - mn);
    m = mn;
  }
  int idx = (b * 8 + blockIdx.y) * 2048 + col;
  pm[idx] = m;
  pl[idx] = l;
}

__global__ void stats2(const float* __restrict__ pm, const float* __restrict__ pl,
                       float* __restrict__ mf, float* __restrict__ lf) {
  int c = blockIdx.x * 256 + threadIdx.x;  // 0..8191 = b*2048+k
  int b = c >> 11, k = c & 2047;
  float m = -1e30f;
  for (int qc = 0; qc < 8; ++qc) m = fmaxf(m, pm[(b * 8 + qc) * 2048 + k]);
  float l = 0.f;
  for (int qc = 0; qc < 8; ++qc)
    l += pl[(b * 8 + qc) * 2048 + k] * __expf(pm[(b * 8 + qc) * 2048 + k] - m);
  mf[c] = m;
  lf[c] = l;
}

__global__ __launch_bounds__(256) void attn_norm(float* __restrict__ S,
                                                 const float* __restrict__ mf,
                                                 const float* __restrict__ lf) {
  long row = blockIdx.x;  // b*2048 + q
  int b = (int)(row >> 11);
  float* Sr = S + row * 2048;
  const float* mb = mf + ((long)b << 11);
  const float* lb = lf + ((long)b << 11);
  for (int c = threadIdx.x * 4; c < 2048; c += 1024) {
    float4 s = *reinterpret_cast<float4*>(&Sr[c]);
    float4 m = *reinterpret_cast<const float4*>(&mb[c]);
    float4 l = *reinterpret_cast<const float4*>(&lb[c]);
    s.x = __expf(s.x - m.x) / l.x;
    s.y = __expf(s.y - m.y) / l.y;
    s.z = __expf(s.z - m.z) / l.z;
    s.w = __expf(s.w - m.w) / l.w;
    *reinterpret_cast<float4*>(&Sr[c]) = s;
  }
}

extern "C" void kernel_launch(void* const* d_in, const int* in_sizes, int n_in,
                              void* d_out, int out_size, void* d_ws, size_t ws_size,
                              hipStream_t stream) {
  const float* query = (const float*)d_in[0];
  const float* key   = (const float*)d_in[1];
  const float* value = (const float*)d_in[2];
  const float* Wq    = (const float*)d_in[3];
  const float* Wk    = (const float*)d_in[4];
  const float* Wv    = (const float*)d_in[5];
  const float* Wo    = (const float*)d_in[6];
  float* out = (float*)d_out;

  float* ws = (float*)d_ws;
  float* Wqt = ws;
  float* Wkt = Wqt + 1024 * 1024;
  float* Wvt = Wkt + 1024 * 1024;
  float* Wot = Wvt + 1024 * 1024;
  float* Qp  = Wot + 1024 * 1024;          // [8192][1024]
  float* Kp  = Qp + 8192L * 1024;          // [8192][1024]
  float* Vt  = Kp + 8192L * 1024;          // [4][1024][2048]
  float* S   = Vt + 8192L * 1024;          // [4][2048][2048]
  float* pm  = S + 4L * 2048 * 2048;
  float* pl  = pm + 8 * 8192;
  float* mf  = pl + 8 * 8192;
  float* lf  = mf + 8192;
  float* head = Qp;  // reuse (Qp dead after scores GEMM)

  dim3 tb(32, 8);
  transpose_k<<<dim3(32, 32), tb, 0, stream>>>(Wq, Wqt, 1024);
  transpose_k<<<dim3(32, 32), tb, 0, stream>>>(Wk, Wkt, 1024);
  transpose_k<<<dim3(32, 32), tb, 0, stream>>>(Wv, Wvt, 1024);
  transpose_k<<<dim3(32, 32), tb, 0, stream>>>(Wo, Wot, 1024);

  // Q = query @ Wq, K = key @ Wk   (M=8192, N=1024, K=1024)
  gemm_nt<1, 0><<<dim3(8, 64, 1), 256, 0, stream>>>(query, Wqt, Qp, 1024, 1024, 1024, 1024, 0, 0, 0, 1.f);
  gemm_nt<1, 0><<<dim3(8, 64, 1), 256, 0, stream>>>(key, Wkt, Kp, 1024, 1024, 1024, 1024, 0, 0, 0, 1.f);
  // V projection, stored transposed per batch: Vt[b][e][s]  (M=2048, N=1024)
  gemm_nt<1, 1><<<dim3(8, 16, 4), 256, 0, stream>>>(value, Wvt, Vt, 1024, 1024, 1024, 2048,
                                                    2048L * 1024, 0, 2048L * 1024, 1.f);
  // scores = 0.125 * Q K^T per batch (M=N=2048, K=1024)
  gemm_nt<1, 0><<<dim3(16, 16, 4), 256, 0, stream>>>(Qp, Kp, S, 1024, 1024, 1024, 2048,
                                                     2048L * 1024, 2048L * 1024, 4L * 1024 * 1024, 0.125f);
  // softmax over q (column-wise stats)
  stats1<<<dim3(8, 8, 4), 256, 0, stream>>>(S, pm, pl);
  stats2<<<dim3(32), 256, 0, stream>>>(pm, pl, mf, lf);
  attn_norm<<<dim3(8192), 256, 0, stream>>>(S, mf, lf);
  // head = attn @ V  (A=S[b], B=Vt[b] as [N=1024][K=2048])
  gemm_nt<1, 0><<<dim3(8, 16, 4), 256, 0, stream>>>(S, Vt, head, 2048, 2048, 2048, 1024,
                                                    4L * 1024 * 1024, 2048L * 1024, 2048L * 1024, 1.f);
  // out = head @ Wo  (M=8192, N=1024, K=1024)
  gemm_nt<1, 0><<<dim3(8, 64, 1), 256, 0, stream>>>(head, Wot, out, 1024, 1024, 1024, 1024, 0, 0, 0, 1.f);
}

// Round 2
// 478.875 us; speedup vs baseline: 1.1938x; 1.1938x over previous
//
#include <hip/hip_runtime.h>

// B=4, S=2048, D=E=1024, DIM=64 -> scale 0.125
// softmax quirk: normalized over the QUERY axis:
//   attn[b,q,k] = exp(s[b,q,k] - m[b,k]) / sum_q' exp(s[b,q',k] - m[b,k])
//
// R2 design: all GEMMs in fp16 MFMA with pre-converted fp16 operands staged
// via global_load_lds(16B). Exp-path GEMMs (Qproj,Kproj,scores) use 3-term
// hi/lo split fp16 (~fp32 accurate); V/PV/out plain fp16. Softmax normalize
// fused into PV A-tile staging (reg-staged exp). XOR swizzle (involution,
// both sides) on LDS tiles.

typedef _Float16 f16;
typedef _Float16 f16x8 __attribute__((ext_vector_type(8)));
typedef float f32x4 __attribute__((ext_vector_type(4)));

#define BM 128
#define BN 128
#define BK 32

__device__ __forceinline__ void gl_lds16(const void* g, void* l) {
  __builtin_amdgcn_global_load_lds(
      (const __attribute__((address_space(1))) void*)(uintptr_t)g,
      (__attribute__((address_space(3))) void*)(uint32_t)(uintptr_t)l, 16, 0, 0);
}

// C[M,N] = scale * A[M,K] * B[N,K]^T  (NT, fp16 operands)
// SPLIT: A,B given as hi+lo pairs, 3-MFMA emulation.
// EXPA : A is fp32 scores; stage exp((s-m[k])*rl[k]) -> fp16 (PV GEMM).
// EPI  : 0 = fp32 C, 1 = fp16 hi/lo pair, 2 = fp16.
template <int SPLIT, int EXPA, int EPI>
__global__ __launch_bounds__(256) void gemm16(
    const f16* __restrict__ Agh, const f16* __restrict__ Agl,
    const f16* __restrict__ Bgh, const f16* __restrict__ Bgl,
    const float* __restrict__ Sf, const float* __restrict__ mf,
    const float* __restrict__ rlf,
    float* __restrict__ Cf, f16* __restrict__ Ch, f16* __restrict__ Cl,
    int K, int ldA, int ldB, int ldC, long sA, long sB, long sC, float scale) {
  __shared__ f16 sAh[BM * BK];
  __shared__ f16 sBh[BN * BK];
  __shared__ f16 sAl[SPLIT ? BM * BK : 8];
  __shared__ f16 sBl[SPLIT ? BN * BK : 8];

  const int tid = threadIdx.x;
  const int lane = tid & 63;
  const int wave = tid >> 6;
  const long bz = blockIdx.z;
  const int tM = blockIdx.y * BM;
  const int tN = blockIdx.x * BN;
  const int wr = (wave >> 1) * 64;
  const int wc = (wave & 1) * 64;
  const int r16 = lane & 15;
  const int q4 = lane >> 4;

  // staging geometry: wave covers 2 chunks of 16 rows; lane -> (row, 16B slot)
  const int srow = wave * 32 + (lane >> 2);
  const int sslot = lane & 3;

  f32x4 acc[4][4] = {};

  for (int kt = 0; kt < K; kt += BK) {
    // ---- stage A tile [128][32] ----
    if constexpr (!EXPA) {
#pragma unroll
      for (int c2 = 0; c2 < 2; ++c2) {
        int row = srow + c2 * 16;
        int src = kt + ((sslot ^ (row & 3)) << 3);  // inverse-swizzled source
        long go = (long)(tM + row) * ldA + src;
        int lo = (wave * 2 + c2) * 512;
        gl_lds16(Agh + bz * sA + go, sAh + lo);
        if constexpr (SPLIT) gl_lds16(Agl + bz * sA + go, sAl + lo);
      }
    } else {
      const float* Sb = Sf + bz * sA;
      const float* mb = mf + bz * 2048;
      const float* rb = rlf + bz * 2048;
#pragma unroll
      for (int rep = 0; rep < 2; ++rep) {
        int row = rep * 64 + (tid >> 2);
        int slot = tid & 3;
        const float* sp = Sb + (long)(tM + row) * ldA + kt + slot * 8;
        float4 a0 = *(const float4*)sp;
        float4 a1 = *(const float4*)(sp + 4);
        float4 m0 = *(const float4*)(mb + kt + slot * 8);
        float4 m1 = *(const float4*)(mb + kt + slot * 8 + 4);
        float4 r0 = *(const float4*)(rb + kt + slot * 8);
        float4 r1 = *(const float4*)(rb + kt + slot * 8 + 4);
        f16x8 v;
        v[0] = (f16)(__expf(a0.x - m0.x) * r0.x);
        v[1] = (f16)(__expf(a0.y - m0.y) * r0.y);
        v[2] = (f16)(__expf(a0.z - m0.z) * r0.z);
        v[3] = (f16)(__expf(a0.w - m0.w) * r0.w);
        v[4] = (f16)(__expf(a1.x - m1.x) * r1.x);
        v[5] = (f16)(__expf(a1.y - m1.y) * r1.y);
        v[6] = (f16)(__expf(a1.z - m1.z) * r1.z);
        v[7] = (f16)(__expf(a1.w - m1.w) * r1.w);
        *(f16x8*)(sAh + row * 32 + ((slot ^ (row & 3)) << 3)) = v;
      }
    }
    // ---- stage B tile [128][32] ----
#pragma unroll
    for (int c2 = 0; c2 < 2; ++c2) {
      int row = srow + c2 * 16;
      int src = kt + ((sslot ^ (row & 3)) << 3);
      long go = (long)(tN + row) * ldB + src;
      int lo = (wave * 2 + c2) * 512;
      gl_lds16(Bgh + bz * sB + go, sBh + lo);
      if constexpr (SPLIT) gl_lds16(Bgl + bz * sB + go, sBl + lo);
    }
    __syncthreads();

    f16x8 ah[4], al[4], bh[4], bl[4];
#pragma unroll
    for (int m = 0; m < 4; ++m) {
      int ar = wr + m * 16 + r16;
      int ao = ar * 32 + ((q4 ^ (ar & 3)) << 3);  // swizzled read
      ah[m] = *(const f16x8*)(sAh + ao);
      if constexpr (SPLIT) al[m] = *(const f16x8*)(sAl + ao);
    }
#pragma unroll
    for (int n = 0; n < 4; ++n) {
      int br = wc + n * 16 + r16;
      int bo = br * 32 + ((q4 ^ (br & 3)) << 3);
      bh[n] = *(const f16x8*)(sBh + bo);
      if constexpr (SPLIT) bl[n] = *(const f16x8*)(sBl + bo);
    }
#pragma unroll
    for (int m = 0; m < 4; ++m)
#pragma unroll
      for (int n = 0; n < 4; ++n) {
        acc[m][n] = __builtin_amdgcn_mfma_f32_16x16x32_f16(ah[m], bh[n], acc[m][n], 0, 0, 0);
        if constexpr (SPLIT) {
          acc[m][n] = __builtin_amdgcn_mfma_f32_16x16x32_f16(ah[m], bl[n], acc[m][n], 0, 0, 0);
          acc[m][n] = __builtin_amdgcn_mfma_f32_16x16x32_f16(al[m], bh[n], acc[m][n], 0, 0, 0);
        }
      }
    __syncthreads();
  }

#pragma unroll
  for (int m = 0; m < 4; ++m)
#pragma unroll
    for (int n = 0; n < 4; ++n)
#pragma unroll
      for (int j = 0; j < 4; ++j) {
        int rr = tM + wr + m * 16 + q4 * 4 + j;
        int cc = tN + wc + n * 16 + r16;
        long off = bz * sC + (long)rr * ldC + cc;
        float v = acc[m][n][j] * scale;
        if constexpr (EPI == 0) {
          Cf[off] = v;
        } else if constexpr (EPI == 1) {
          f16 hv = (f16)v;
          Ch[off] = hv;
          Cl[off] = (f16)(v - (float)hv);
        } else {
          Ch[off] = (f16)v;
        }
      }
}

// fp32 -> fp16 (hi [+lo]) conversion, 8 elems/thread
template <int SPLIT>
__global__ __launch_bounds__(256) void convert(const float* __restrict__ in,
                                               f16* __restrict__ hi,
                                               f16* __restrict__ lo, long n) {
  long i = ((long)blockIdx.x * 256 + threadIdx.x) * 8;
  if (i >= n) return;
  float4 a = *(const float4*)(in + i);
  float4 b = *(const float4*)(in + i + 4);
  float va[8] = {a.x, a.y, a.z, a.w, b.x, b.y, b.z, b.w};
  f16x8 h;
#pragma unroll
  for (int j = 0; j < 8; ++j) h[j] = (f16)va[j];
  *(f16x8*)(hi + i) = h;
  if constexpr (SPLIT) {
    f16x8 l;
#pragma unroll
    for (int j = 0; j < 8; ++j) l[j] = (f16)(va[j] - (float)h[j]);
    *(f16x8*)(lo + i) = l;
  }
}

// transpose + fp16 convert (n x n)
template <int SPLIT>
__global__ void tconv(const float* __restrict__ in, f16* __restrict__ hi,
                      f16* __restrict__ lo, int n) {
  __shared__ float t[32][33];
  int bx = blockIdx.x * 32, by = blockIdx.y * 32;
  int tx = threadIdx.x, ty = threadIdx.y;  // 32 x 8
  for (int i = 0; i < 32; i += 8) t[ty + i][tx] = in[(long)(by + ty + i) * n + bx + tx];
  __syncthreads();
  for (int i = 0; i < 32; i += 8) {
    float v = t[tx][ty + i];
    f16 h = (f16)v;
    hi[(long)(bx + ty + i) * n + by + tx] = h;
    if constexpr (SPLIT) lo[(long)(bx + ty + i) * n + by + tx] = (f16)(v - (float)h);
  }
}

// per-column (over q) online max/sum, partial over 256-row chunk
__global__ __launch_bounds__(256) void stats1(const float* __restrict__ S,
                                              float* __restrict__ pm, float* __restrict__ pl) {
  int b = blockIdx.z;
  int col = blockIdx.x * 256 + threadIdx.x;
  int q0 = blockIdx.y * 256;
  const float* Sb = S + (long)b * 2048 * 2048;
  float m = -1e30f, l = 0.f;
  for (int i = 0; i < 256; ++i) {
    float s = Sb[(long)(q0 + i) * 2048 + col];
    float mn = fmaxf(m, s);
    l = l * __expf(m - mn) + __expf(s - mn);
    m = mn;
  }
  int idx = (b * 8 + blockIdx.y) * 2048 + col;
  pm[idx] = m;
  pl[idx] = l;
}

__global__ void stats2(const float* __restrict__ pm, const float* __restrict__ pl,
                       float* __restrict__ mfo, float* __restrict__ rlo) {
  int c = blockIdx.x * 256 + threadIdx.x;  // b*2048 + k
  int b = c >> 11, k = c & 2047;
  float m = -1e30f;
  for (int qc = 0; qc < 8; ++qc) m = fmaxf(m, pm[(b * 8 + qc) * 2048 + k]);
  float l = 0.f;
  for (int qc = 0; qc < 8; ++qc)
    l += pl[(b * 8 + qc) * 2048 + k] * __expf(pm[(b * 8 + qc) * 2048 + k] - m);
  mfo[c] = m;
  rlo[c] = 1.f / l;
}

extern "C" void kernel_launch(void* const* d_in, const int* in_sizes, int n_in,
                              void* d_out, int out_size, void* d_ws, size_t ws_size,
                              hipStream_t stream) {
  const float* query = (const float*)d_in[0];
  const float* key   = (const float*)d_in[1];
  const float* value = (const float*)d_in[2];
  const float* Wq    = (const float*)d_in[3];
  const float* Wk    = (const float*)d_in[4];
  const float* Wv    = (const float*)d_in[5];
  const float* Wo    = (const float*)d_in[6];
  float* out = (float*)d_out;

  // arena (f16-element offsets). S (fp32, 33.55M f16-elems) overlays the prep
  // region [in16,v16,W's] which is dead before the scores GEMM. Total 153.7MB.
  f16* h = (f16*)d_ws;
  const long E8 = 8388608L;  // 8192*1024
  const long E1 = 1048576L;  // 1024*1024
  f16* in16h = h;
  f16* in16l = h + E8;
  f16* v16   = h + 2 * E8;
  f16* Wqth  = h + 3 * E8;
  f16* Wqtl  = Wqth + E1;
  f16* Wkth  = Wqtl + E1;
  f16* Wktl  = Wkth + E1;
  f16* Wvt   = Wktl + E1;                 // ends 30,408,704 < 33,554,432
  float* S   = (float*)d_ws;              // [0 .. 33,554,432) f16-elems
  f16* Wot   = h + 33554432L;
  float* fst = (float*)(h + 33554432L + E1);
  float* pm  = fst;            // 65536
  float* pl  = pm + 65536;     // 65536
  float* mf  = pl + 65536;     // 8192
  float* rl  = mf + 8192;      // 8192
  f16* Qh = h + 34897920L;
  f16* Ql = Qh + E8;
  f16* Kh = Ql + E8;
  f16* Kl = Kh + E8;
  f16* Vt16 = Kl + E8;         // 4*1024*2048
  f16* h16 = Qh;               // reuse (Q dead after scores)

  dim3 tb32(32, 8);
  tconv<1><<<dim3(32, 32), tb32, 0, stream>>>(Wq, Wqth, Wqtl, 1024);
  tconv<1><<<dim3(32, 32), tb32, 0, stream>>>(Wk, Wkth, Wktl, 1024);
  tconv<0><<<dim3(32, 32), tb32, 0, stream>>>(Wv, Wvt, nullptr, 1024);
  tconv<0><<<dim3(32, 32), tb32, 0, stream>>>(Wo, Wot, nullptr, 1024);

  // Q projection (split): Qh/Ql = query @ Wq
  convert<1><<<4096, 256, 0, stream>>>(query, in16h, in16l, E8);
  gemm16<1, 0, 1><<<dim3(8, 64, 1), 256, 0, stream>>>(
      in16h, in16l, Wqth, Wqtl, nullptr, nullptr, nullptr,
      nullptr, Qh, Ql, 1024, 1024, 1024, 1024, 0, 0, 0, 1.f);
  // K projection (split)
  convert<1><<<4096, 256, 0, stream>>>(key, in16h, in16l, E8);
  gemm16<1, 0, 1><<<dim3(8, 64, 1), 256, 0, stream>>>(
      in16h, in16l, Wkth, Wktl, nullptr, nullptr, nullptr,
      nullptr, Kh, Kl, 1024, 1024, 1024, 1024, 0, 0, 0, 1.f);
  // V projection (plain), output transposed per batch: Vt[b][e][s]
  convert<0><<<4096, 256, 0, stream>>>(value, v16, nullptr, E8);
  gemm16<0, 0, 2><<<dim3(16, 8, 4), 256, 0, stream>>>(
      Wvt, nullptr, v16, nullptr, nullptr, nullptr, nullptr,
      nullptr, Vt16, nullptr, 1024, 1024, 1024, 2048, 0, 2097152L, 2097152L, 1.f);
  // scores = 0.125 * Q K^T (split, fp32 out)
  gemm16<1, 0, 0><<<dim3(16, 16, 4), 256, 0, stream>>>(
      Qh, Ql, Kh, Kl, nullptr, nullptr, nullptr,
      S, nullptr, nullptr, 1024, 1024, 1024, 2048, 2097152L, 2097152L, 4194304L, 0.125f);
  // softmax-over-q stats
  stats1<<<dim3(8, 8, 4), 256, 0, stream>>>(S, pm, pl);
  stats2<<<32, 256, 0, stream>>>(pm, pl, mf, rl);
  // head = attn @ V with normalize fused into A staging (fp16 out)
  gemm16<0, 1, 2><<<dim3(8, 16, 4), 256, 0, stream>>>(
      nullptr, nullptr, Vt16, nullptr, S, mf, rl,
      nullptr, h16, nullptr, 2048, 2048, 2048, 1024, 4194304L, 2097152L, 2097152L, 1.f);
  // out = head @ Wo (fp32 out)
  gemm16<0, 0, 0><<<dim3(8, 64, 1), 256, 0, stream>>>(
      h16, nullptr, Wot, nullptr, nullptr, nullptr, nullptr,
      out, nullptr, nullptr, 1024, 1024, 1024, 1024, 0, 0, 0, 1.f);
}

// Round 3
// 363.486 us; speedup vs baseline: 1.5727x; 1.3175x over previous
//
#include <hip/hip_runtime.h>

// B=4, S=2048, D=E=1024, DIM=64 -> scale 0.125
// softmax quirk: normalized over the QUERY axis:
//   attn[b,q,k] = exp(s[b,q,k] - m[b,k]) / sum_q' exp(s[b,q',k] - m[b,k])
//
// R3: ALL GEMMs plain fp16 MFMA (no hi/lo split). fp32->fp16 prep passes,
// global_load_lds(16B) staging, XOR-swizzled LDS (involution on both sides).
// Softmax normalize fused into PV A-staging. fp32 accumulate throughout.

typedef _Float16 f16;
typedef _Float16 f16x8 __attribute__((ext_vector_type(8)));
typedef float f32x4 __attribute__((ext_vector_type(4)));

#define BM 128
#define BN 128
#define BK 32

__device__ __forceinline__ void gl_lds16(const void* g, void* l) {
  __builtin_amdgcn_global_load_lds(
      (const __attribute__((address_space(1))) void*)(uintptr_t)g,
      (__attribute__((address_space(3))) void*)(uint32_t)(uintptr_t)l, 16, 0, 0);
}

// C[M,N] = scale * A[M,K] * B[N,K]^T  (NT, fp16 operands, fp32 accum)
// EXPA: A is fp32 scores; stage exp((s-m[k])*rl[k]) -> fp16 (PV GEMM).
// EPI : 0 = fp32 C, 2 = fp16 C.
template <int EXPA, int EPI>
__global__ __launch_bounds__(256) void gemm16(
    const f16* __restrict__ Ag, const f16* __restrict__ Bg,
    const float* __restrict__ Sf, const float* __restrict__ mf,
    const float* __restrict__ rlf,
    float* __restrict__ Cf, f16* __restrict__ Ch,
    int K, int ldA, int ldB, int ldC, long sA, long sB, long sC, float scale) {
  __shared__ f16 sAh[BM * BK];
  __shared__ f16 sBh[BN * BK];

  const int tid = threadIdx.x;
  const int lane = tid & 63;
  const int wave = tid >> 6;
  const long bz = blockIdx.z;
  const int tM = blockIdx.y * BM;
  const int tN = blockIdx.x * BN;
  const int wr = (wave >> 1) * 64;
  const int wc = (wave & 1) * 64;
  const int r16 = lane & 15;
  const int q4 = lane >> 4;

  // staging geometry: wave covers 2 chunks of 16 rows; lane -> (row, 16B slot)
  const int srow = wave * 32 + (lane >> 2);
  const int sslot = lane & 3;

  f32x4 acc[4][4] = {};

  for (int kt = 0; kt < K; kt += BK) {
    // ---- stage A tile [128][32] ----
    if constexpr (!EXPA) {
#pragma unroll
      for (int c2 = 0; c2 < 2; ++c2) {
        int row = srow + c2 * 16;
        int src = kt + ((sslot ^ (row & 3)) << 3);  // inverse-swizzled source
        long go = (long)(tM + row) * ldA + src;
        int lo = (wave * 2 + c2) * 512;
        gl_lds16(Ag + bz * sA + go, sAh + lo);
      }
    } else {
      const float* Sb = Sf + bz * sA;
      const float* mb = mf + bz * 2048;
      const float* rb = rlf + bz * 2048;
#pragma unroll
      for (int rep = 0; rep < 2; ++rep) {
        int row = rep * 64 + (tid >> 2);
        int slot = tid & 3;
        const float* sp = Sb + (long)(tM + row) * ldA + kt + slot * 8;
        float4 a0 = *(const float4*)sp;
        float4 a1 = *(const float4*)(sp + 4);
        float4 m0 = *(const float4*)(mb + kt + slot * 8);
        float4 m1 = *(const float4*)(mb + kt + slot * 8 + 4);
        float4 r0 = *(const float4*)(rb + kt + slot * 8);
        float4 r1 = *(const float4*)(rb + kt + slot * 8 + 4);
        f16x8 v;
        v[0] = (f16)(__expf(a0.x - m0.x) * r0.x);
        v[1] = (f16)(__expf(a0.y - m0.y) * r0.y);
        v[2] = (f16)(__expf(a0.z - m0.z) * r0.z);
        v[3] = (f16)(__expf(a0.w - m0.w) * r0.w);
        v[4] = (f16)(__expf(a1.x - m1.x) * r1.x);
        v[5] = (f16)(__expf(a1.y - m1.y) * r1.y);
        v[6] = (f16)(__expf(a1.z - m1.z) * r1.z);
        v[7] = (f16)(__expf(a1.w - m1.w) * r1.w);
        *(f16x8*)(sAh + row * 32 + ((slot ^ (row & 3)) << 3)) = v;
      }
    }
    // ---- stage B tile [128][32] ----
#pragma unroll
    for (int c2 = 0; c2 < 2; ++c2) {
      int row = srow + c2 * 16;
      int src = kt + ((sslot ^ (row & 3)) << 3);
      long go = (long)(tN + row) * ldB + src;
      int lo = (wave * 2 + c2) * 512;
      gl_lds16(Bg + bz * sB + go, sBh + lo);
    }
    __syncthreads();

    f16x8 ah[4], bh[4];
#pragma unroll
    for (int m = 0; m < 4; ++m) {
      int ar = wr + m * 16 + r16;
      ah[m] = *(const f16x8*)(sAh + ar * 32 + ((q4 ^ (ar & 3)) << 3));
    }
#pragma unroll
    for (int n = 0; n < 4; ++n) {
      int br = wc + n * 16 + r16;
      bh[n] = *(const f16x8*)(sBh + br * 32 + ((q4 ^ (br & 3)) << 3));
    }
#pragma unroll
    for (int m = 0; m < 4; ++m)
#pragma unroll
      for (int n = 0; n < 4; ++n)
        acc[m][n] = __builtin_amdgcn_mfma_f32_16x16x32_f16(ah[m], bh[n], acc[m][n], 0, 0, 0);
    __syncthreads();
  }

#pragma unroll
  for (int m = 0; m < 4; ++m)
#pragma unroll
    for (int n = 0; n < 4; ++n)
#pragma unroll
      for (int j = 0; j < 4; ++j) {
        int rr = tM + wr + m * 16 + q4 * 4 + j;
        int cc = tN + wc + n * 16 + r16;
        long off = bz * sC + (long)rr * ldC + cc;
        float v = acc[m][n][j] * scale;
        if constexpr (EPI == 0)
          Cf[off] = v;
        else
          Ch[off] = (f16)v;
      }
}

// fp32 -> fp16 conversion, 8 elems/thread
__global__ __launch_bounds__(256) void convert(const float* __restrict__ in,
                                               f16* __restrict__ hi, long n) {
  long i = ((long)blockIdx.x * 256 + threadIdx.x) * 8;
  if (i >= n) return;
  float4 a = *(const float4*)(in + i);
  float4 b = *(const float4*)(in + i + 4);
  f16x8 h;
  h[0] = (f16)a.x; h[1] = (f16)a.y; h[2] = (f16)a.z; h[3] = (f16)a.w;
  h[4] = (f16)b.x; h[5] = (f16)b.y; h[6] = (f16)b.z; h[7] = (f16)b.w;
  *(f16x8*)(hi + i) = h;
}

// transpose + fp16 convert (n x n)
__global__ void tconv(const float* __restrict__ in, f16* __restrict__ hi, int n) {
  __shared__ float t[32][33];
  int bx = blockIdx.x * 32, by = blockIdx.y * 32;
  int tx = threadIdx.x, ty = threadIdx.y;  // 32 x 8
  for (int i = 0; i < 32; i += 8) t[ty + i][tx] = in[(long)(by + ty + i) * n + bx + tx];
  __syncthreads();
  for (int i = 0; i < 32; i += 8)
    hi[(long)(bx + ty + i) * n + by + tx] = (f16)t[tx][ty + i];
}

// per-column (over q) online max/sum, partial over 256-row chunk
__global__ __launch_bounds__(256) void stats1(const float* __restrict__ S,
                                              float* __restrict__ pm, float* __restrict__ pl) {
  int b = blockIdx.z;
  int col = blockIdx.x * 256 + threadIdx.x;
  int q0 = blockIdx.y * 256;
  const float* Sb = S + (long)b * 2048 * 2048;
  float m = -1e30f, l = 0.f;
  for (int i = 0; i < 256; ++i) {
    float s = Sb[(long)(q0 + i) * 2048 + col];
    float mn = fmaxf(m, s);
    l = l * __expf(m - mn) + __expf(s - mn);
    m = mn;
  }
  int idx = (b * 8 + blockIdx.y) * 2048 + col;
  pm[idx] = m;
  pl[idx] = l;
}

__global__ void stats2(const float* __restrict__ pm, const float* __restrict__ pl,
                       float* __restrict__ mfo, float* __restrict__ rlo) {
  int c = blockIdx.x * 256 + threadIdx.x;  // b*2048 + k
  int b = c >> 11, k = c & 2047;
  float m = -1e30f;
  for (int qc = 0; qc < 8; ++qc) m = fmaxf(m, pm[(b * 8 + qc) * 2048 + k]);
  float l = 0.f;
  for (int qc = 0; qc < 8; ++qc)
    l += pl[(b * 8 + qc) * 2048 + k] * __expf(pm[(b * 8 + qc) * 2048 + k] - m);
  mfo[c] = m;
  rlo[c] = 1.f / l;
}

extern "C" void kernel_launch(void* const* d_in, const int* in_sizes, int n_in,
                              void* d_out, int out_size, void* d_ws, size_t ws_size,
                              hipStream_t stream) {
  const float* query = (const float*)d_in[0];
  const float* key   = (const float*)d_in[1];
  const float* value = (const float*)d_in[2];
  const float* Wq    = (const float*)d_in[3];
  const float* Wk    = (const float*)d_in[4];
  const float* Wv    = (const float*)d_in[5];
  const float* Wo    = (const float*)d_in[6];
  float* out = (float*)d_out;

  // arena (f16-element offsets), total ~160 MB
  f16* h = (f16*)d_ws;
  const long E8 = 8388608L;  // 8192*1024
  const long E1 = 1048576L;  // 1024*1024
  f16* in16 = h;             // query/key staging; later reused for head
  f16* v16  = in16 + E8;
  f16* Qh   = v16 + E8;
  f16* Kh   = Qh + E8;
  f16* Vt16 = Kh + E8;       // [4][1024][2048]
  f16* Wqt  = Vt16 + E8;
  f16* Wkt  = Wqt + E1;
  f16* Wvt  = Wkt + E1;
  f16* Wot  = Wvt + E1;
  float* S  = (float*)(Wot + E1);  // [4][2048][2048] fp32
  float* pm = S + 16777216L;       // 8*8192
  float* pl = pm + 65536;
  float* mf = pl + 65536;
  float* rl = mf + 8192;
  f16* h16 = in16;  // reuse (inputs dead after projections)

  dim3 tb32(32, 8);
  tconv<<<dim3(32, 32), tb32, 0, stream>>>(Wq, Wqt, 1024);
  tconv<<<dim3(32, 32), tb32, 0, stream>>>(Wk, Wkt, 1024);
  tconv<<<dim3(32, 32), tb32, 0, stream>>>(Wv, Wvt, 1024);
  tconv<<<dim3(32, 32), tb32, 0, stream>>>(Wo, Wot, 1024);

  // Q = query @ Wq  (M=8192, N=1024, K=1024), fp16 out
  convert<<<4096, 256, 0, stream>>>(query, in16, E8);
  gemm16<0, 2><<<dim3(8, 64, 1), 256, 0, stream>>>(
      in16, Wqt, nullptr, nullptr, nullptr, nullptr, Qh,
      1024, 1024, 1024, 1024, 0, 0, 0, 1.f);
  // K = key @ Wk
  convert<<<4096, 256, 0, stream>>>(key, in16, E8);
  gemm16<0, 2><<<dim3(8, 64, 1), 256, 0, stream>>>(
      in16, Wkt, nullptr, nullptr, nullptr, nullptr, Kh,
      1024, 1024, 1024, 1024, 0, 0, 0, 1.f);
  // V projection, stored transposed per batch: Vt[b][e][s]  (A=Wvt M=1024, B=value N=2048)
  convert<<<4096, 256, 0, stream>>>(value, v16, E8);
  gemm16<0, 2><<<dim3(16, 8, 4), 256, 0, stream>>>(
      Wvt, v16, nullptr, nullptr, nullptr, nullptr, Vt16,
      1024, 1024, 1024, 2048, 0, 2097152L, 2097152L, 1.f);
  // scores = 0.125 * Q K^T per batch (M=N=2048, K=1024), fp32 out
  gemm16<0, 0><<<dim3(16, 16, 4), 256, 0, stream>>>(
      Qh, Kh, nullptr, nullptr, nullptr, S, nullptr,
      1024, 1024, 1024, 2048, 2097152L, 2097152L, 4194304L, 0.125f);
  // softmax-over-q stats
  stats1<<<dim3(8, 8, 4), 256, 0, stream>>>(S, pm, pl);
  stats2<<<32, 256, 0, stream>>>(pm, pl, mf, rl);
  // head = attn @ V with normalize fused into A staging (fp16 out)
  gemm16<1, 2><<<dim3(8, 16, 4), 256, 0, stream>>>(
      nullptr, Vt16, S, mf, rl, nullptr, h16,
      2048, 2048, 2048, 1024, 4194304L, 2097152L, 2097152L, 1.f);
  // out = head @ Wo (fp32 out)
  gemm16<0, 0><<<dim3(8, 64, 1), 256, 0, stream>>>(
      h16, Wot, nullptr, nullptr, nullptr, out, nullptr,
      1024, 1024, 1024, 1024, 0, 0, 0, 1.f);
}

// Round 5
// 337.635 us; speedup vs baseline: 1.6931x; 1.0766x over previous
//
#include <hip/hip_runtime.h>

// B=4, S=2048, D=E=1024, DIM=64 -> scale 0.125
// softmax quirk: normalized over the QUERY axis:
//   attn[b,q,k] = exp(s[b,q,k] - m[b,k]) / sum_q' exp(s[b,q',k] - m[b,k])
//
// R4b: all GEMMs plain fp16 MFMA, gl_lds(16B) staging, XOR-swizzled LDS.
// Scores written fp16; softmax stats from fp16 S (quantization cancels in
// normalization); attn = exp(s-m)*rl materialized fp16 IN PLACE; PV is then
// a plain fp16 GEMM (no exp in K-loop, no fp32 S re-reads).

typedef _Float16 f16;
typedef _Float16 f16x8 __attribute__((ext_vector_type(8)));
typedef float f32x4 __attribute__((ext_vector_type(4)));

#define BM 128
#define BN 128
#define BK 32

__device__ __forceinline__ void gl_lds16(const void* g, void* l) {
  __builtin_amdgcn_global_load_lds(
      (const __attribute__((address_space(1))) void*)(uintptr_t)g,
      (__attribute__((address_space(3))) void*)(uint32_t)(uintptr_t)l, 16, 0, 0);
}

// C[M,N] = scale * A[M,K] * B[N,K]^T  (NT, fp16 operands, fp32 accum)
// EPI : 0 = fp32 C, 2 = fp16 C.
template <int EPI>
__global__ __launch_bounds__(256) void gemm16(
    const f16* __restrict__ Ag, const f16* __restrict__ Bg,
    float* __restrict__ Cf, f16* __restrict__ Ch,
    int K, int ldA, int ldB, int ldC, long sA, long sB, long sC, float scale) {
  __shared__ f16 sAh[BM * BK];
  __shared__ f16 sBh[BN * BK];

  const int tid = threadIdx.x;
  const int lane = tid & 63;
  const int wave = tid >> 6;
  const long bz = blockIdx.z;
  const int tM = blockIdx.y * BM;
  const int tN = blockIdx.x * BN;
  const int wr = (wave >> 1) * 64;
  const int wc = (wave & 1) * 64;
  const int r16 = lane & 15;
  const int q4 = lane >> 4;

  // staging geometry: wave covers 2 chunks of 16 rows; lane -> (row, 16B slot)
  const int srow = wave * 32 + (lane >> 2);
  const int sslot = lane & 3;

  f32x4 acc[4][4] = {};

  for (int kt = 0; kt < K; kt += BK) {
#pragma unroll
    for (int c2 = 0; c2 < 2; ++c2) {
      int row = srow + c2 * 16;
      int src = kt + ((sslot ^ (row & 3)) << 3);  // inverse-swizzled source
      int lo = (wave * 2 + c2) * 512;
      gl_lds16(Ag + bz * sA + (long)(tM + row) * ldA + src, sAh + lo);
      gl_lds16(Bg + bz * sB + (long)(tN + row) * ldB + src, sBh + lo);
    }
    __syncthreads();

    f16x8 ah[4], bh[4];
#pragma unroll
    for (int m = 0; m < 4; ++m) {
      int ar = wr + m * 16 + r16;
      ah[m] = *(const f16x8*)(sAh + ar * 32 + ((q4 ^ (ar & 3)) << 3));
    }
#pragma unroll
    for (int n = 0; n < 4; ++n) {
      int br = wc + n * 16 + r16;
      bh[n] = *(const f16x8*)(sBh + br * 32 + ((q4 ^ (br & 3)) << 3));
    }
#pragma unroll
    for (int m = 0; m < 4; ++m)
#pragma unroll
      for (int n = 0; n < 4; ++n)
        acc[m][n] = __builtin_amdgcn_mfma_f32_16x16x32_f16(ah[m], bh[n], acc[m][n], 0, 0, 0);
    __syncthreads();
  }

#pragma unroll
  for (int m = 0; m < 4; ++m)
#pragma unroll
    for (int n = 0; n < 4; ++n)
#pragma unroll
      for (int j = 0; j < 4; ++j) {
        int rr = tM + wr + m * 16 + q4 * 4 + j;
        int cc = tN + wc + n * 16 + r16;
        long off = bz * sC + (long)rr * ldC + cc;
        float v = acc[m][n][j] * scale;
        if constexpr (EPI == 0)
          Cf[off] = v;
        else
          Ch[off] = (f16)v;
      }
}

// fp32 -> fp16 conversion, 8 elems/thread
__global__ __launch_bounds__(256) void convert(const float* __restrict__ in,
                                               f16* __restrict__ hi, long n) {
  long i = ((long)blockIdx.x * 256 + threadIdx.x) * 8;
  if (i >= n) return;
  float4 a = *(const float4*)(in + i);
  float4 b = *(const float4*)(in + i + 4);
  f16x8 h;
  h[0] = (f16)a.x; h[1] = (f16)a.y; h[2] = (f16)a.z; h[3] = (f16)a.w;
  h[4] = (f16)b.x; h[5] = (f16)b.y; h[6] = (f16)b.z; h[7] = (f16)b.w;
  *(f16x8*)(hi + i) = h;
}

// transpose + fp16 convert (n x n)
__global__ void tconv(const float* __restrict__ in, f16* __restrict__ hi, int n) {
  __shared__ float t[32][33];
  int bx = blockIdx.x * 32, by = blockIdx.y * 32;
  int tx = threadIdx.x, ty = threadIdx.y;  // 32 x 8
  for (int i = 0; i < 32; i += 8) t[ty + i][tx] = in[(long)(by + ty + i) * n + bx + tx];
  __syncthreads();
  for (int i = 0; i < 32; i += 8)
    hi[(long)(bx + ty + i) * n + by + tx] = (f16)t[tx][ty + i];
}

// per-column (over q) online max/sum from fp16 S; 32-row chunks, 8 cols/thread
__global__ __launch_bounds__(256) void stats1(const f16* __restrict__ S16,
                                              float* __restrict__ pm, float* __restrict__ pl) {
  int b = blockIdx.z;
  int q0 = blockIdx.y * 32;
  int c0 = threadIdx.x * 8;
  const f16* Sb = S16 + (long)b * 4194304;
  float m[8], l[8];
#pragma unroll
  for (int j = 0; j < 8; ++j) { m[j] = -1e30f; l[j] = 0.f; }
  for (int i = 0; i < 32; ++i) {
    f16x8 v = *(const f16x8*)(Sb + (long)(q0 + i) * 2048 + c0);
#pragma unroll
    for (int j = 0; j < 8; ++j) {
      float s = (float)v[j];
      float mn = fmaxf(m[j], s);
      l[j] = l[j] * __expf(m[j] - mn) + __expf(s - mn);
      m[j] = mn;
    }
  }
  int base = (b * 64 + blockIdx.y) * 2048 + c0;
#pragma unroll
  for (int j = 0; j < 8; ++j) { pm[base + j] = m[j]; pl[base + j] = l[j]; }
}

__global__ void stats2(const float* __restrict__ pm, const float* __restrict__ pl,
                       float* __restrict__ mfo, float* __restrict__ rlo) {
  int c = blockIdx.x * 256 + threadIdx.x;  // b*2048 + k
  int b = c >> 11, k = c & 2047;
  float m = -1e30f;
  for (int qc = 0; qc < 64; ++qc) m = fmaxf(m, pm[(b * 64 + qc) * 2048 + k]);
  float l = 0.f;
  for (int qc = 0; qc < 64; ++qc)
    l += pl[(b * 64 + qc) * 2048 + k] * __expf(pm[(b * 64 + qc) * 2048 + k] - m);
  mfo[c] = m;
  rlo[c] = 1.f / l;
}

// in-place: S16 <- exp(S16 - m[col]) * rl[col]   (fp16)
__global__ __launch_bounds__(256) void norm(f16* __restrict__ S16,
                                            const float* __restrict__ mf,
                                            const float* __restrict__ rl) {
  long row = blockIdx.x;  // b*2048 + q
  int b = (int)(row >> 11);
  f16* Sr = S16 + row * 2048;
  const float* mb = mf + ((long)b << 11);
  const float* rb = rl + ((long)b << 11);
  int c = threadIdx.x * 8;
  f16x8 v = *(f16x8*)(Sr + c);
  float4 m0 = *(const float4*)(mb + c);
  float4 m1 = *(const float4*)(mb + c + 4);
  float4 r0 = *(const float4*)(rb + c);
  float4 r1 = *(const float4*)(rb + c + 4);
  f16x8 o;
  o[0] = (f16)(__expf((float)v[0] - m0.x) * r0.x);
  o[1] = (f16)(__expf((float)v[1] - m0.y) * r0.y);
  o[2] = (f16)(__expf((float)v[2] - m0.z) * r0.z);
  o[3] = (f16)(__expf((float)v[3] - m0.w) * r0.w);
  o[4] = (f16)(__expf((float)v[4] - m1.x) * r1.x);
  o[5] = (f16)(__expf((float)v[5] - m1.y) * r1.y);
  o[6] = (f16)(__expf((float)v[6] - m1.z) * r1.z);
  o[7] = (f16)(__expf((float)v[7] - m1.w) * r1.w);
  *(f16x8*)(Sr + c) = o;
}

extern "C" void kernel_launch(void* const* d_in, const int* in_sizes, int n_in,
                              void* d_out, int out_size, void* d_ws, size_t ws_size,
                              hipStream_t stream) {
  const float* query = (const float*)d_in[0];
  const float* key   = (const float*)d_in[1];
  const float* value = (const float*)d_in[2];
  const float* Wq    = (const float*)d_in[3];
  const float* Wk    = (const float*)d_in[4];
  const float* Wv    = (const float*)d_in[5];
  const float* Wo    = (const float*)d_in[6];
  float* out = (float*)d_out;

  // arena (f16-element offsets), total ~130 MB
  f16* h = (f16*)d_ws;
  const long E8 = 8388608L;  // 8192*1024
  const long E1 = 1048576L;  // 1024*1024
  f16* in16 = h;             // query/key/value staging; later reused for head
  f16* v16  = in16 + E8;
  f16* Qh   = v16 + E8;
  f16* Kh   = Qh + E8;
  f16* Vt16 = Kh + E8;       // [4][1024][2048]
  f16* Wqt  = Vt16 + E8;
  f16* Wkt  = Wqt + E1;
  f16* Wvt  = Wkt + E1;
  f16* Wot  = Wvt + E1;
  f16* S16  = Wot + E1;      // [4][2048][2048] fp16 scores -> attn (in place)
  float* pm = (float*)(S16 + 16777216L);  // [4][64][2048]
  float* pl = pm + 524288;
  float* mf = pl + 524288;   // 8192
  float* rl = mf + 8192;
  f16* h16 = in16;           // reuse (inputs dead after projections)

  dim3 tb32(32, 8);
  tconv<<<dim3(32, 32), tb32, 0, stream>>>(Wq, Wqt, 1024);
  tconv<<<dim3(32, 32), tb32, 0, stream>>>(Wk, Wkt, 1024);
  tconv<<<dim3(32, 32), tb32, 0, stream>>>(Wv, Wvt, 1024);
  tconv<<<dim3(32, 32), tb32, 0, stream>>>(Wo, Wot, 1024);

  // Q = query @ Wq  (M=8192, N=1024, K=1024), fp16 out
  convert<<<4096, 256, 0, stream>>>(query, in16, E8);
  gemm16<2><<<dim3(8, 64, 1), 256, 0, stream>>>(
      in16, Wqt, nullptr, Qh, 1024, 1024, 1024, 1024, 0, 0, 0, 1.f);
  // K = key @ Wk
  convert<<<4096, 256, 0, stream>>>(key, in16, E8);
  gemm16<2><<<dim3(8, 64, 1), 256, 0, stream>>>(
      in16, Wkt, nullptr, Kh, 1024, 1024, 1024, 1024, 0, 0, 0, 1.f);
  // V projection, stored transposed per batch: Vt[b][e][s]
  convert<<<4096, 256, 0, stream>>>(value, v16, E8);
  gemm16<2><<<dim3(16, 8, 4), 256, 0, stream>>>(
      Wvt, v16, nullptr, Vt16, 1024, 1024, 1024, 2048, 0, 2097152L, 2097152L, 1.f);
  // scores = 0.125 * Q K^T per batch (M=N=2048, K=1024), fp16 out
  gemm16<2><<<dim3(16, 16, 4), 256, 0, stream>>>(
      Qh, Kh, nullptr, S16, 1024, 1024, 1024, 2048, 2097152L, 2097152L, 4194304L, 0.125f);
  // softmax-over-q stats from fp16 S
  stats1<<<dim3(1, 64, 4), 256, 0, stream>>>(S16, pm, pl);
  stats2<<<32, 256, 0, stream>>>(pm, pl, mf, rl);
  // attn = exp(s - m) * rl, fp16 in place
  norm<<<8192, 256, 0, stream>>>(S16, mf, rl);
  // head = attn @ V (plain fp16 GEMM now)
  gemm16<2><<<dim3(8, 16, 4), 256, 0, stream>>>(
      S16, Vt16, nullptr, h16, 2048, 2048, 2048, 1024, 4194304L, 2097152L, 2097152L, 1.f);
  // out = head @ Wo (fp32 out)
  gemm16<0><<<dim3(8, 64, 1), 256, 0, stream>>>(
      h16, Wot, out, nullptr, 1024, 1024, 1024, 1024, 0, 0, 0, 1.f);
}

// Round 6
// 298.941 us; speedup vs baseline: 1.9123x; 1.1294x over previous
//
#include <hip/hip_runtime.h>

// B=4, S=2048, D=E=1024, DIM=64 -> scale 0.125
// softmax quirk: normalized over the QUERY axis:
//   attn[b,q,k] = exp(s[b,q,k] - m[b,k]) / sum_q' exp(s[b,q',k] - m[b,k])
//
// R6: Wo folded into V path (out = attn @ (value @ (Wv*Wo))) -> 4 GEMM stages:
//   Wvo = Wv*Wo (tiny), batched {Q,K,VWo} projections (z=3), scores, final.
// fp16 MFMA, BK=64, gl_lds(16B), full 8-slot XOR swizzle (conflict-free).

typedef _Float16 f16;
typedef _Float16 f16x8 __attribute__((ext_vector_type(8)));
typedef float f32x4 __attribute__((ext_vector_type(4)));

#define BM 128
#define BN 128
#define BK 64

__device__ __forceinline__ void gl_lds16(const void* g, void* l) {
  __builtin_amdgcn_global_load_lds(
      (const __attribute__((address_space(1))) void*)(uintptr_t)g,
      (__attribute__((address_space(3))) void*)(uint32_t)(uintptr_t)l, 16, 0, 0);
}

// C[M,N] = scale * A[M,K] * B[N,K]^T  (NT, fp16 operands, fp32 accum)
// EPI: 0 = fp32 C; 2 = fp16 C; 3 = fp16 C transposed (C[cc*ldC+rr]);
//      4 = fp16 C, but z==2 writes per-batch transposed [b][cc][rr&2047]
//          at base Ch + 2*sC (projection batch: Q, K, VWo^T).
template <int EPI>
__global__ __launch_bounds__(256) void gemm16(
    const f16* __restrict__ Ag, const f16* __restrict__ Bg,
    float* __restrict__ Cf, f16* __restrict__ Ch,
    int K, int ldA, int ldB, int ldC, long sA, long sB, long sC, float scale) {
  __shared__ f16 sA_[BM * BK];
  __shared__ f16 sB_[BN * BK];

  const int tid = threadIdx.x;
  const int lane = tid & 63;
  const int wave = tid >> 6;
  const long bz = blockIdx.z;
  const int tM = blockIdx.y * BM;
  const int tN = blockIdx.x * BN;
  const int wr = (wave >> 1) * 64;
  const int wc = (wave & 1) * 64;
  const int r16 = lane & 15;
  const int q4 = lane >> 4;

  const f16* Abase = Ag + bz * sA;
  const f16* Bbase = Bg + bz * sB;

  f32x4 acc[4][4] = {};

  for (int kt = 0; kt < K; kt += BK) {
    // stage A,B tiles [128][64] f16; LDS linear, source col pre-swizzled
    // LDS[row][s] = G[row][s ^ (row&7)]  (8 slots x 16B -> all 32 banks)
#pragma unroll
    for (int it = 0; it < 4; ++it) {
      int row = it * 32 + (tid >> 3);
      int s = tid & 7;
      int gcol = kt + ((s ^ (row & 7)) << 3);
      int lo = row * 64 + s * 8;  // = it*2048 + wave*512 + lane*8 (uniform+lane*16B)
      gl_lds16(Abase + (long)(tM + row) * ldA + gcol, sA_ + lo);
      gl_lds16(Bbase + (long)(tN + row) * ldB + gcol, sB_ + lo);
    }
    __syncthreads();

#pragma unroll
    for (int kk = 0; kk < 2; ++kk) {
      f16x8 ah[4], bh[4];
#pragma unroll
      for (int m = 0; m < 4; ++m) {
        int ar = wr + m * 16 + r16;
        int q = kk * 4 + q4;
        ah[m] = *(const f16x8*)(sA_ + ar * 64 + ((q ^ (ar & 7)) << 3));
      }
#pragma unroll
      for (int n = 0; n < 4; ++n) {
        int br = wc + n * 16 + r16;
        int q = kk * 4 + q4;
        bh[n] = *(const f16x8*)(sB_ + br * 64 + ((q ^ (br & 7)) << 3));
      }
#pragma unroll
      for (int m = 0; m < 4; ++m)
#pragma unroll
        for (int n = 0; n < 4; ++n)
          acc[m][n] = __builtin_amdgcn_mfma_f32_16x16x32_f16(ah[m], bh[n], acc[m][n], 0, 0, 0);
    }
    __syncthreads();
  }

#pragma unroll
  for (int m = 0; m < 4; ++m)
#pragma unroll
    for (int n = 0; n < 4; ++n)
#pragma unroll
      for (int j = 0; j < 4; ++j) {
        int rr = tM + wr + m * 16 + q4 * 4 + j;
        int cc = tN + wc + n * 16 + r16;
        float v = acc[m][n][j] * scale;
        if constexpr (EPI == 0) {
          Cf[bz * sC + (long)rr * ldC + cc] = v;
        } else if constexpr (EPI == 2) {
          Ch[bz * sC + (long)rr * ldC + cc] = (f16)v;
        } else if constexpr (EPI == 3) {
          Ch[(long)cc * ldC + rr] = (f16)v;
        } else {  // EPI == 4: projection batch
          if (bz == 2)
            Ch[2 * sC + (long)cc * 2048 + (long)(rr >> 11) * 2097152L + (rr & 2047)] = (f16)v;
          else
            Ch[bz * sC + (long)rr * ldC + cc] = (f16)v;
        }
      }
}

// fp32 -> fp16 conversion, 8 elems/thread
__global__ __launch_bounds__(256) void convert(const float* __restrict__ in,
                                               f16* __restrict__ hi, long n) {
  long i = ((long)blockIdx.x * 256 + threadIdx.x) * 8;
  if (i >= n) return;
  float4 a = *(const float4*)(in + i);
  float4 b = *(const float4*)(in + i + 4);
  f16x8 h;
  h[0] = (f16)a.x; h[1] = (f16)a.y; h[2] = (f16)a.z; h[3] = (f16)a.w;
  h[4] = (f16)b.x; h[5] = (f16)b.y; h[6] = (f16)b.z; h[7] = (f16)b.w;
  *(f16x8*)(hi + i) = h;
}

// transpose + fp16 convert (n x n)
__global__ void tconv(const float* __restrict__ in, f16* __restrict__ hi, int n) {
  __shared__ float t[32][33];
  int bx = blockIdx.x * 32, by = blockIdx.y * 32;
  int tx = threadIdx.x, ty = threadIdx.y;  // 32 x 8
  for (int i = 0; i < 32; i += 8) t[ty + i][tx] = in[(long)(by + ty + i) * n + bx + tx];
  __syncthreads();
  for (int i = 0; i < 32; i += 8)
    hi[(long)(bx + ty + i) * n + by + tx] = (f16)t[tx][ty + i];
}

// per-column (over q) online max/sum from fp16 S; 32-row chunks, 8 cols/thread
__global__ __launch_bounds__(256) void stats1(const f16* __restrict__ S16,
                                              float* __restrict__ pm, float* __restrict__ pl) {
  int b = blockIdx.z;
  int q0 = blockIdx.y * 32;
  int c0 = threadIdx.x * 8;
  const f16* Sb = S16 + (long)b * 4194304;
  float m[8], l[8];
#pragma unroll
  for (int j = 0; j < 8; ++j) { m[j] = -1e30f; l[j] = 0.f; }
  for (int i = 0; i < 32; ++i) {
    f16x8 v = *(const f16x8*)(Sb + (long)(q0 + i) * 2048 + c0);
#pragma unroll
    for (int j = 0; j < 8; ++j) {
      float s = (float)v[j];
      float mn = fmaxf(m[j], s);
      l[j] = l[j] * __expf(m[j] - mn) + __expf(s - mn);
      m[j] = mn;
    }
  }
  int base = (b * 64 + blockIdx.y) * 2048 + c0;
#pragma unroll
  for (int j = 0; j < 8; ++j) { pm[base + j] = m[j]; pl[base + j] = l[j]; }
}

__global__ void stats2(const float* __restrict__ pm, const float* __restrict__ pl,
                       float* __restrict__ mfo, float* __restrict__ rlo) {
  int c = blockIdx.x * 256 + threadIdx.x;  // b*2048 + k
  int b = c >> 11, k = c & 2047;
  float m = -1e30f;
  for (int qc = 0; qc < 64; ++qc) m = fmaxf(m, pm[(b * 64 + qc) * 2048 + k]);
  float l = 0.f;
  for (int qc = 0; qc < 64; ++qc)
    l += pl[(b * 64 + qc) * 2048 + k] * __expf(pm[(b * 64 + qc) * 2048 + k] - m);
  mfo[c] = m;
  rlo[c] = 1.f / l;
}

// in-place: S16 <- exp(S16 - m[col]) * rl[col]   (fp16)
__global__ __launch_bounds__(256) void norm(f16* __restrict__ S16,
                                            const float* __restrict__ mf,
                                            const float* __restrict__ rl) {
  long row = blockIdx.x;  // b*2048 + q
  int b = (int)(row >> 11);
  f16* Sr = S16 + row * 2048;
  const float* mb = mf + ((long)b << 11);
  const float* rb = rl + ((long)b << 11);
  int c = threadIdx.x * 8;
  f16x8 v = *(f16x8*)(Sr + c);
  float4 m0 = *(const float4*)(mb + c);
  float4 m1 = *(const float4*)(mb + c + 4);
  float4 r0 = *(const float4*)(rb + c);
  float4 r1 = *(const float4*)(rb + c + 4);
  f16x8 o;
  o[0] = (f16)(__expf((float)v[0] - m0.x) * r0.x);
  o[1] = (f16)(__expf((float)v[1] - m0.y) * r0.y);
  o[2] = (f16)(__expf((float)v[2] - m0.z) * r0.z);
  o[3] = (f16)(__expf((float)v[3] - m0.w) * r0.w);
  o[4] = (f16)(__expf((float)v[4] - m1.x) * r1.x);
  o[5] = (f16)(__expf((float)v[5] - m1.y) * r1.y);
  o[6] = (f16)(__expf((float)v[6] - m1.z) * r1.z);
  o[7] = (f16)(__expf((float)v[7] - m1.w) * r1.w);
  *(f16x8*)(Sr + c) = o;
}

extern "C" void kernel_launch(void* const* d_in, const int* in_sizes, int n_in,
                              void* d_out, int out_size, void* d_ws, size_t ws_size,
                              hipStream_t stream) {
  const float* query = (const float*)d_in[0];
  const float* key   = (const float*)d_in[1];
  const float* value = (const float*)d_in[2];
  const float* Wq    = (const float*)d_in[3];
  const float* Wk    = (const float*)d_in[4];
  const float* Wv    = (const float*)d_in[5];
  const float* Wo    = (const float*)d_in[6];
  float* out = (float*)d_out;

  // arena (f16-element offsets), ~144 MB
  f16* h = (f16*)d_ws;
  const long E8 = 8388608L;  // 8192*1024
  const long E1 = 1048576L;  // 1024*1024
  f16* q16   = h;            // contiguous A-batch for proj: q16,k16,v16
  f16* k16   = h + E8;
  f16* v16   = h + 2 * E8;
  f16* Qh    = h + 3 * E8;   // contiguous C-batch: Qh, Kh, VWoT
  f16* Kh    = h + 4 * E8;
  f16* VWoT  = h + 5 * E8;   // [4][1024][2048]
  f16* Wqt   = h + 6 * E8;   // contiguous B-batch: Wqt, Wkt, Wvot
  f16* Wkt   = Wqt + E1;
  f16* Wvot  = Wkt + E1;
  f16* Wot   = Wvot + E1;
  f16* wv16  = Wot + E1;
  f16* S16   = wv16 + E1;    // [4][2048][2048] fp16 scores -> attn (in place)
  float* pm  = (float*)(S16 + 16777216L);  // [4][64][2048]
  float* pl  = pm + 524288;
  float* mf  = pl + 524288;  // 8192
  float* rl  = mf + 8192;

  dim3 tb32(32, 8);
  tconv<<<dim3(32, 32), tb32, 0, stream>>>(Wq, Wqt, 1024);
  tconv<<<dim3(32, 32), tb32, 0, stream>>>(Wk, Wkt, 1024);
  tconv<<<dim3(32, 32), tb32, 0, stream>>>(Wo, Wot, 1024);
  convert<<<512, 256, 0, stream>>>(Wv, wv16, E1);

  // Wvo^T = (Wv @ Wo)^T  (M=N=K=1024, TRANS epilogue)
  gemm16<3><<<dim3(8, 8, 1), 256, 0, stream>>>(
      wv16, Wot, nullptr, Wvot, 1024, 1024, 1024, 1024, 0, 0, 0, 1.f);

  // input conversions
  convert<<<4096, 256, 0, stream>>>(query, q16, E8);
  convert<<<4096, 256, 0, stream>>>(key, k16, E8);
  convert<<<4096, 256, 0, stream>>>(value, v16, E8);

  // batched projections z=3: z0 Q=query@Wq, z1 K=key@Wk, z2 VWo=value@Wvo
  // (z2 written per-batch transposed: VWoT[b][e][s])
  gemm16<4><<<dim3(8, 64, 3), 256, 0, stream>>>(
      q16, Wqt, nullptr, Qh, 1024, 1024, 1024, 1024, E8, E1, E8, 1.f);

  // scores = 0.125 * Q K^T per batch (M=N=2048, K=1024), fp16 out
  gemm16<2><<<dim3(16, 16, 4), 256, 0, stream>>>(
      Qh, Kh, nullptr, S16, 1024, 1024, 1024, 2048, 2097152L, 2097152L, 4194304L, 0.125f);

  // softmax-over-q stats from fp16 S, then normalize in place
  stats1<<<dim3(1, 64, 4), 256, 0, stream>>>(S16, pm, pl);
  stats2<<<32, 256, 0, stream>>>(pm, pl, mf, rl);
  norm<<<8192, 256, 0, stream>>>(S16, mf, rl);

  // out = attn @ VWo per batch (M=2048, N=1024, K=2048), fp32 out
  gemm16<0><<<dim3(8, 16, 4), 256, 0, stream>>>(
      S16, VWoT, out, nullptr, 2048, 2048, 2048, 1024, 4194304L, 2097152L, 2097152L, 1.f);
}

// Round 8
// 284.618 us; speedup vs baseline: 2.0085x; 1.0503x over previous
//
#include <hip/hip_runtime.h>

// B=4, S=2048, D=E=1024, DIM=64 -> scale 0.125
// softmax quirk: normalized over the QUERY axis:
//   attn[b,q,k] = exp(s[b,q,k] - m[b,k]) / sum_q' exp(s[b,q',k] - m[b,k])
//
// R8 = R7 with the tail-race fix: staged tile index is CLAMPED (t-2, same
// parity) instead of skipped, so per-iteration gl_lds issue counts are
// uniform and the ph4/ph8 vmcnt(N) always drains through tile T+1.
// 256-row-tile 8-phase counted-vmcnt GEMM (T2+T3+T4+T5), BM=256, BK=64,
// BN in {256,128}, 512 thr (8 waves 2x4), dbuf'd {A0,A1,B0,B1} half-tiles.
// Pipeline: Wvo=Wv@Wo fold (out = attn @ (value@Wvo)); batched {Q,K,VWo} proj;
// fp16 scores; softmax-over-q stats + in-place normalize; final attn@VWo.

typedef _Float16 f16;
typedef _Float16 f16x8 __attribute__((ext_vector_type(8)));
typedef float f32x4 __attribute__((ext_vector_type(4)));

__device__ __forceinline__ void gl_lds16(const void* g, void* l) {
  __builtin_amdgcn_global_load_lds(
      (const __attribute__((address_space(1))) void*)(uintptr_t)g,
      (__attribute__((address_space(3))) void*)(uint32_t)(uintptr_t)l, 16, 0, 0);
}

#define BARR __builtin_amdgcn_s_barrier()
#define PRIO1 __builtin_amdgcn_s_setprio(1)
#define PRIO0 __builtin_amdgcn_s_setprio(0)
#define LGKM0                                          \
  do {                                                 \
    asm volatile("s_waitcnt lgkmcnt(0)" ::: "memory"); \
    __builtin_amdgcn_sched_barrier(0);                 \
  } while (0)

#define MFQ(Q)                                                                 \
  {                                                                            \
    _Pragma("unroll") for (int m2 = 0; m2 < 2; ++m2)                           \
        _Pragma("unroll") for (int n = 0; n < NF; ++n)                         \
            _Pragma("unroll") for (int kk = 0; kk < 2; ++kk) acc[(Q)*2 + m2]   \
        [n] = __builtin_amdgcn_mfma_f32_16x16x32_f16(                          \
            a[((Q)*2 + m2) * 2 + kk], b[n * 2 + kk], acc[(Q)*2 + m2][n], 0, 0, \
            0);                                                                \
  }

// C[M,N] = scale * A[M,K]*B[N,K]^T  (NT layout, fp16 in, fp32 accum)
// EPI: 0 = fp32 C; 2 = fp16 C; 4 = fp16 C, z==2 written per-batch transposed
//      (projection batch: Q, K, VWo^T).
template <int BN, int EPI>
__global__ __launch_bounds__(512, 2) void gemm256(
    const f16* __restrict__ Ag, const f16* __restrict__ Bg,
    float* __restrict__ Cf, f16* __restrict__ Ch,
    int K, int ldA, int ldB, int ldC, long sA, long sB, long sC, float scale) {
  constexpr int NF = BN / 64;        // b-frags per wave
  constexpr int LB = BN / 128;       // gl_lds loads per B-half
  constexpr int AH = 128 * 64;       // f16 per A-half
  constexpr int BH = (BN / 2) * 64;  // f16 per B-half
  constexpr int DB = 2 * AH + 2 * BH;
  __shared__ f16 lds[2 * DB];

  const int tid = threadIdx.x;
  const int lane = tid & 63;
  const int wave = tid >> 6;
  const long bz = blockIdx.z;
  const int tM = blockIdx.y * 256;
  const int tN = blockIdx.x * BN;
  const int wr = wave >> 2;   // 0..1
  const int wc = wave & 3;    // 0..3
  const int r16 = lane & 15;
  const int q4 = lane >> 4;

  const f16* Abase = Ag + bz * sA;
  const f16* Bbase = Bg + bz * sB;
  const int NT = K >> 6;

  f16x8 a[16];
  f16x8 b[2 * NF];
  f32x4 acc[8][NF] = {};

  // Clamped stage: for t >= NT re-stage tile t-2 (same parity -> same dbuf,
  // already consumed) so gl_lds issue counts are IDENTICAL every iteration
  // and the counted vmcnt always drains through tile T+1.
  auto stA = [&](int t, int half) {
    int tc = (t < NT) ? t : (t - 2);
    f16* dst = lds + (t & 1) * DB + half * AH;
    const f16* g = Abase + (long)(tM + half * 128) * ldA + tc * 64;
#pragma unroll
    for (int l = 0; l < 2; ++l) {
      int r = l * 64 + wave * 8 + (lane >> 3);
      int s = lane & 7;
      gl_lds16(g + (long)r * ldA + ((s ^ (r & 7)) << 3), dst + r * 64 + s * 8);
    }
  };
  auto stB = [&](int t, int half) {
    int tc = (t < NT) ? t : (t - 2);
    f16* dst = lds + (t & 1) * DB + 2 * AH + half * BH;
    const f16* g = Bbase + (long)(tN + half * (BN / 2)) * ldB + tc * 64;
#pragma unroll
    for (int l = 0; l < LB; ++l) {
      int r = l * 64 + wave * 8 + (lane >> 3);
      int s = lane & 7;
      gl_lds16(g + (long)r * ldB + ((s ^ (r & 7)) << 3), dst + r * 64 + s * 8);
    }
  };
  auto readT = [&](int t) {
    const f16* db = lds + (t & 1) * DB;
    const f16* ah = db + wr * AH;
#pragma unroll
    for (int m = 0; m < 8; ++m)
#pragma unroll
      for (int kk = 0; kk < 2; ++kk) {
        int arl = m * 16 + r16;
        a[m * 2 + kk] =
            *(const f16x8*)(ah + arl * 64 + ((((kk << 2) + q4) ^ (arl & 7)) << 3));
      }
#pragma unroll
    for (int n = 0; n < NF; ++n)
#pragma unroll
      for (int kk = 0; kk < 2; ++kk) {
        int colg = wc * (BN / 4) + n * 16 + r16;
        const f16* bh = db + 2 * AH + (colg / (BN / 2)) * BH;
        int brl = colg % (BN / 2);
        b[n * 2 + kk] =
            *(const f16x8*)(bh + brl * 64 + ((((kk << 2) + q4) ^ (brl & 7)) << 3));
      }
  };

#define VMW                                                       \
  do {                                                            \
    if constexpr (BN == 256)                                      \
      asm volatile("s_waitcnt vmcnt(6)" ::: "memory");            \
    else                                                          \
      asm volatile("s_waitcnt vmcnt(5)" ::: "memory");            \
  } while (0)

  // prologue: tile0 all 4 halves, tile1 A0,A1,B0
  stA(0, 0); stA(0, 1); stB(0, 0); stB(0, 1);
  stA(1, 0); stA(1, 1); stB(1, 0);
  VMW;
  BARR;

  for (int T = 0; T < NT; T += 2) {
    // ph1: read tile T (dbuf0), stage B1 of T+1
    readT(T);
    stB(T + 1, 1);
    BARR; LGKM0; PRIO1; MFQ(0); PRIO0; BARR;
    // ph2
    stA(T + 2, 0);
    BARR; PRIO1; MFQ(1); PRIO0; BARR;
    // ph3
    stA(T + 2, 1);
    BARR; PRIO1; MFQ(2); PRIO0; BARR;
    // ph4
    stB(T + 2, 0);
    BARR; PRIO1; MFQ(3); PRIO0; VMW; BARR;
    // ph5: read tile T+1 (dbuf1), stage B1 of T+2
    readT(T + 1);
    stB(T + 2, 1);
    BARR; LGKM0; PRIO1; MFQ(0); PRIO0; BARR;
    // ph6
    stA(T + 3, 0);
    BARR; PRIO1; MFQ(1); PRIO0; BARR;
    // ph7
    stA(T + 3, 1);
    BARR; PRIO1; MFQ(2); PRIO0; BARR;
    // ph8
    stB(T + 3, 0);
    BARR; PRIO1; MFQ(3); PRIO0; VMW; BARR;
  }
#undef VMW

#pragma unroll
  for (int m = 0; m < 8; ++m)
#pragma unroll
    for (int n = 0; n < NF; ++n)
#pragma unroll
      for (int j = 0; j < 4; ++j) {
        int rr = tM + wr * 128 + m * 16 + q4 * 4 + j;
        int cc = tN + wc * (BN / 4) + n * 16 + r16;
        float v = acc[m][n][j] * scale;
        if constexpr (EPI == 0) {
          Cf[bz * sC + (long)rr * ldC + cc] = v;
        } else if constexpr (EPI == 2) {
          Ch[bz * sC + (long)rr * ldC + cc] = (f16)v;
        } else {  // EPI == 4
          if (bz == 2)
            Ch[2 * sC + (long)cc * 2048 + (long)(rr >> 11) * 2097152L + (rr & 2047)] = (f16)v;
          else
            Ch[bz * sC + (long)rr * ldC + cc] = (f16)v;
        }
      }
}

// small 128x128-tile GEMM for Wvo = (Wv @ Wo)^T  (fp16, transposed store)
__global__ __launch_bounds__(256) void gemm_wvo(
    const f16* __restrict__ Ag, const f16* __restrict__ Bg, f16* __restrict__ Ch,
    int K, int ldA, int ldB, int ldC) {
  __shared__ f16 sA_[128 * 64];
  __shared__ f16 sB_[128 * 64];
  const int tid = threadIdx.x;
  const int lane = tid & 63;
  const int wave = tid >> 6;
  const int tM = blockIdx.y * 128;
  const int tN = blockIdx.x * 128;
  const int wr = (wave >> 1) * 64;
  const int wc = (wave & 1) * 64;
  const int r16 = lane & 15;
  const int q4 = lane >> 4;
  f32x4 acc[4][4] = {};
  for (int kt = 0; kt < K; kt += 64) {
#pragma unroll
    for (int it = 0; it < 4; ++it) {
      int row = it * 32 + (tid >> 3);
      int s = tid & 7;
      int gcol = kt + ((s ^ (row & 7)) << 3);
      int lo = row * 64 + s * 8;
      gl_lds16(Ag + (long)(tM + row) * ldA + gcol, sA_ + lo);
      gl_lds16(Bg + (long)(tN + row) * ldB + gcol, sB_ + lo);
    }
    __syncthreads();
#pragma unroll
    for (int kk = 0; kk < 2; ++kk) {
      f16x8 ah[4], bh[4];
#pragma unroll
      for (int m = 0; m < 4; ++m) {
        int ar = wr + m * 16 + r16;
        ah[m] = *(const f16x8*)(sA_ + ar * 64 + (((kk * 4 + q4) ^ (ar & 7)) << 3));
      }
#pragma unroll
      for (int n = 0; n < 4; ++n) {
        int br = wc + n * 16 + r16;
        bh[n] = *(const f16x8*)(sB_ + br * 64 + (((kk * 4 + q4) ^ (br & 7)) << 3));
      }
#pragma unroll
      for (int m = 0; m < 4; ++m)
#pragma unroll
        for (int n = 0; n < 4; ++n)
          acc[m][n] = __builtin_amdgcn_mfma_f32_16x16x32_f16(ah[m], bh[n], acc[m][n], 0, 0, 0);
    }
    __syncthreads();
  }
#pragma unroll
  for (int m = 0; m < 4; ++m)
#pragma unroll
    for (int n = 0; n < 4; ++n)
#pragma unroll
      for (int j = 0; j < 4; ++j) {
        int rr = tM + wr + m * 16 + q4 * 4 + j;
        int cc = tN + wc + n * 16 + r16;
        Ch[(long)cc * ldC + rr] = (f16)acc[m][n][j];
      }
}

// fp32 -> fp16 conversion, 8 elems/thread
__global__ __launch_bounds__(256) void convert(const float* __restrict__ in,
                                               f16* __restrict__ hi, long n) {
  long i = ((long)blockIdx.x * 256 + threadIdx.x) * 8;
  if (i >= n) return;
  float4 aa = *(const float4*)(in + i);
  float4 bb = *(const float4*)(in + i + 4);
  f16x8 h;
  h[0] = (f16)aa.x; h[1] = (f16)aa.y; h[2] = (f16)aa.z; h[3] = (f16)aa.w;
  h[4] = (f16)bb.x; h[5] = (f16)bb.y; h[6] = (f16)bb.z; h[7] = (f16)bb.w;
  *(f16x8*)(hi + i) = h;
}

// transpose + fp16 convert (n x n)
__global__ void tconv(const float* __restrict__ in, f16* __restrict__ hi, int n) {
  __shared__ float t[32][33];
  int bx = blockIdx.x * 32, by = blockIdx.y * 32;
  int tx = threadIdx.x, ty = threadIdx.y;  // 32 x 8
  for (int i = 0; i < 32; i += 8) t[ty + i][tx] = in[(long)(by + ty + i) * n + bx + tx];
  __syncthreads();
  for (int i = 0; i < 32; i += 8)
    hi[(long)(bx + ty + i) * n + by + tx] = (f16)t[tx][ty + i];
}

// per-column (over q) online max/sum from fp16 S; 32-row chunks, 8 cols/thread
__global__ __launch_bounds__(256) void stats1(const f16* __restrict__ S16,
                                              float* __restrict__ pm, float* __restrict__ pl) {
  int b = blockIdx.z;
  int q0 = blockIdx.y * 32;
  int c0 = threadIdx.x * 8;
  const f16* Sb = S16 + (long)b * 4194304;
  float m[8], l[8];
#pragma unroll
  for (int j = 0; j < 8; ++j) { m[j] = -1e30f; l[j] = 0.f; }
  for (int i = 0; i < 32; ++i) {
    f16x8 v = *(const f16x8*)(Sb + (long)(q0 + i) * 2048 + c0);
#pragma unroll
    for (int j = 0; j < 8; ++j) {
      float s = (float)v[j];
      float mn = fmaxf(m[j], s);
      l[j] = l[j] * __expf(m[j] - mn) + __expf(s - mn);
      m[j] = mn;
    }
  }
  int base = (b * 64 + blockIdx.y) * 2048 + c0;
#pragma unroll
  for (int j = 0; j < 8; ++j) { pm[base + j] = m[j]; pl[base + j] = l[j]; }
}

__global__ void stats2(const float* __restrict__ pm, const float* __restrict__ pl,
                       float* __restrict__ mfo, float* __restrict__ rlo) {
  int c = blockIdx.x * 256 + threadIdx.x;  // b*2048 + k
  int b = c >> 11, k = c & 2047;
  float m = -1e30f;
  for (int qc = 0; qc < 64; ++qc) m = fmaxf(m, pm[(b * 64 + qc) * 2048 + k]);
  float l = 0.f;
  for (int qc = 0; qc < 64; ++qc)
    l += pl[(b * 64 + qc) * 2048 + k] * __expf(pm[(b * 64 + qc) * 2048 + k] - m);
  mfo[c] = m;
  rlo[c] = 1.f / l;
}

// in-place: S16 <- exp(S16 - m[col]) * rl[col]   (fp16)
__global__ __launch_bounds__(256) void norm(f16* __restrict__ S16,
                                            const float* __restrict__ mf,
                                            const float* __restrict__ rl) {
  long row = blockIdx.x;  // b*2048 + q
  int b = (int)(row >> 11);
  f16* Sr = S16 + row * 2048;
  const float* mb = mf + ((long)b << 11);
  const float* rb = rl + ((long)b << 11);
  int c = threadIdx.x * 8;
  f16x8 v = *(f16x8*)(Sr + c);
  float4 m0 = *(const float4*)(mb + c);
  float4 m1 = *(const float4*)(mb + c + 4);
  float4 r0 = *(const float4*)(rb + c);
  float4 r1 = *(const float4*)(rb + c + 4);
  f16x8 o;
  o[0] = (f16)(__expf((float)v[0] - m0.x) * r0.x);
  o[1] = (f16)(__expf((float)v[1] - m0.y) * r0.y);
  o[2] = (f16)(__expf((float)v[2] - m0.z) * r0.z);
  o[3] = (f16)(__expf((float)v[3] - m0.w) * r0.w);
  o[4] = (f16)(__expf((float)v[4] - m1.x) * r1.x);
  o[5] = (f16)(__expf((float)v[5] - m1.y) * r1.y);
  o[6] = (f16)(__expf((float)v[6] - m1.z) * r1.z);
  o[7] = (f16)(__expf((float)v[7] - m1.w) * r1.w);
  *(f16x8*)(Sr + c) = o;
}

extern "C" void kernel_launch(void* const* d_in, const int* in_sizes, int n_in,
                              void* d_out, int out_size, void* d_ws, size_t ws_size,
                              hipStream_t stream) {
  const float* query = (const float*)d_in[0];
  const float* key   = (const float*)d_in[1];
  const float* value = (const float*)d_in[2];
  const float* Wq    = (const float*)d_in[3];
  const float* Wk    = (const float*)d_in[4];
  const float* Wv    = (const float*)d_in[5];
  const float* Wo    = (const float*)d_in[6];
  float* out = (float*)d_out;

  // arena (f16-element offsets), ~144 MB
  f16* h = (f16*)d_ws;
  const long E8 = 8388608L;  // 8192*1024
  const long E1 = 1048576L;  // 1024*1024
  f16* q16   = h;            // contiguous A-batch for proj: q16,k16,v16
  f16* k16   = h + E8;
  f16* v16   = h + 2 * E8;
  f16* Qh    = h + 3 * E8;   // contiguous C-batch: Qh, Kh, VWoT
  f16* Kh    = h + 4 * E8;
  f16* VWoT  = h + 5 * E8;   // [4][1024][2048]
  f16* Wqt   = h + 6 * E8;   // contiguous B-batch: Wqt, Wkt, Wvot
  f16* Wkt   = Wqt + E1;
  f16* Wvot  = Wkt + E1;
  f16* Wot   = Wvot + E1;
  f16* wv16  = Wot + E1;
  f16* S16   = wv16 + E1;    // [4][2048][2048] fp16 scores -> attn (in place)
  float* pm  = (float*)(S16 + 16777216L);  // [4][64][2048]
  float* pl  = pm + 524288;
  float* mf  = pl + 524288;  // 8192
  float* rl  = mf + 8192;
  (void)in_sizes; (void)n_in; (void)out_size; (void)ws_size;

  dim3 tb32(32, 8);
  tconv<<<dim3(32, 32), tb32, 0, stream>>>(Wq, Wqt, 1024);
  tconv<<<dim3(32, 32), tb32, 0, stream>>>(Wk, Wkt, 1024);
  tconv<<<dim3(32, 32), tb32, 0, stream>>>(Wo, Wot, 1024);
  convert<<<512, 256, 0, stream>>>(Wv, wv16, E1);

  // Wvo^T = (Wv @ Wo)^T  (M=N=K=1024)
  gemm_wvo<<<dim3(8, 8, 1), 256, 0, stream>>>(wv16, Wot, Wvot, 1024, 1024, 1024, 1024);

  // input conversions
  convert<<<4096, 256, 0, stream>>>(query, q16, E8);
  convert<<<4096, 256, 0, stream>>>(key, k16, E8);
  convert<<<4096, 256, 0, stream>>>(value, v16, E8);

  // batched projections z=3: z0 Q=query@Wq, z1 K=key@Wk, z2 VWo=value@Wvo
  // (z2 written per-batch transposed: VWoT[b][e][s]) -- 768 blocks
  gemm256<128, 4><<<dim3(8, 32, 3), 512, 0, stream>>>(
      q16, Wqt, nullptr, Qh, 1024, 1024, 1024, 1024, E8, E1, E8, 1.f);

  // scores = 0.125 * Q K^T per batch (M=N=2048, K=1024), fp16 out -- 256 blocks
  gemm256<256, 2><<<dim3(8, 8, 4), 512, 0, stream>>>(
      Qh, Kh, nullptr, S16, 1024, 1024, 1024, 2048, 2097152L, 2097152L, 4194304L, 0.125f);

  // softmax-over-q stats from fp16 S, then normalize in place
  stats1<<<dim3(1, 64, 4), 256, 0, stream>>>(S16, pm, pl);
  stats2<<<32, 256, 0, stream>>>(pm, pl, mf, rl);
  norm<<<8192, 256, 0, stream>>>(S16, mf, rl);

  // out = attn @ VWo per batch (M=2048, N=1024, K=2048), fp32 out -- 256 blocks
  gemm256<128, 0><<<dim3(8, 8, 4), 512, 0, stream>>>(
      S16, VWoT, out, nullptr, 2048, 2048, 2048, 1024, 4194304L, 2097152L, 2097152L, 1.f);
}